// Round 5
// baseline (234.545 us; speedup 1.0000x reference)
//
#include <hip/hip_runtime.h>
#include <hip/hip_cooperative_groups.h>
#include <math.h>

namespace cg = cooperative_groups;

#define NN 768
#define DD 128
#define AA 312
#define HH 8
#define CEPS 1e-8f
#define SMEM_F 5920

typedef __attribute__((ext_vector_type(8))) short s8b;   // 8 x bf16
typedef __attribute__((ext_vector_type(4))) float f4v;   // MFMA C/D

__device__ __forceinline__ float wave_sum(float v) {
    #pragma unroll
    for (int o = 32; o; o >>= 1) v += __shfl_down(v, o, 64);
    return v;
}
__device__ __forceinline__ float wave_max(float v) {
    #pragma unroll
    for (int o = 32; o; o >>= 1) v = fmaxf(v, __shfl_down(v, o, 64));
    return v;
}
__device__ __forceinline__ unsigned short f2bf(float f) {
    unsigned u = __float_as_uint(f);
    u += 0x7FFFu + ((u >> 16) & 1u);
    return (unsigned short)(u >> 16);
}

struct KParams {
    const float *visual, *semantic, *attribute;
    const float *Wvn, *bvn, *gvn, *betavn, *Wve1, *bve1, *Wve2, *bve2;
    const float *Wsn, *bsn, *gsn, *betasn, *Wse1, *bse1, *Wse2, *bse2;
    float *vp, *sp, *ve2, *se2;
    float *simv, *sima, *WvnT, *WsnT, *cvec1, *cvec2;
    short *vpb, *spb;
};

// ---------------- gram tile: 256-thread 32x32 tile (tid in [0,256)) ----------------
template <int COLS>
__device__ void gram_tile(const float* __restrict__ A, float invtemp, float* __restrict__ sim,
                          int i0, int j0, int tid, float* As, float* Bs) {
    const int tx = tid & 15, ty = tid >> 4;
    const int lr = tid >> 3, lc4 = (tid & 7) * 4;
    float acc00 = 0.f, acc01 = 0.f, acc10 = 0.f, acc11 = 0.f;
    float si0 = 0.f, si1 = 0.f, sj0 = 0.f, sj1 = 0.f;
    for (int kc = 0; kc < COLS; kc += 32) {
        float4 av, bv;
        if (kc + lc4 + 4 <= COLS) {
            av = *(const float4*)(A + (size_t)(i0 + lr) * COLS + kc + lc4);
            bv = *(const float4*)(A + (size_t)(j0 + lr) * COLS + kc + lc4);
        } else {
            float ta[4], tb[4];
            #pragma unroll
            for (int l = 0; l < 4; ++l) {
                int c = kc + lc4 + l;
                ta[l] = (c < COLS) ? A[(size_t)(i0 + lr) * COLS + c] : 0.f;
                tb[l] = (c < COLS) ? A[(size_t)(j0 + lr) * COLS + c] : 0.f;
            }
            av = make_float4(ta[0], ta[1], ta[2], ta[3]);
            bv = make_float4(tb[0], tb[1], tb[2], tb[3]);
        }
        __syncthreads();
        As[(lc4 + 0) * 34 + lr] = av.x; As[(lc4 + 1) * 34 + lr] = av.y;
        As[(lc4 + 2) * 34 + lr] = av.z; As[(lc4 + 3) * 34 + lr] = av.w;
        Bs[(lc4 + 0) * 34 + lr] = bv.x; Bs[(lc4 + 1) * 34 + lr] = bv.y;
        Bs[(lc4 + 2) * 34 + lr] = bv.z; Bs[(lc4 + 3) * 34 + lr] = bv.w;
        __syncthreads();
        #pragma unroll
        for (int k = 0; k < 32; ++k) {
            float2 aa = *(const float2*)&As[k * 34 + 2 * ty];
            float2 bb = *(const float2*)&Bs[k * 34 + 2 * tx];
            acc00 = fmaf(aa.x, bb.x, acc00);
            acc01 = fmaf(aa.x, bb.y, acc01);
            acc10 = fmaf(aa.y, bb.x, acc10);
            acc11 = fmaf(aa.y, bb.y, acc11);
            si0 = fmaf(aa.x, aa.x, si0);
            si1 = fmaf(aa.y, aa.y, si1);
            sj0 = fmaf(bb.x, bb.x, sj0);
            sj1 = fmaf(bb.y, bb.y, sj1);
        }
    }
    const float ni0 = sqrtf(si0), ni1 = sqrtf(si1);
    const float nj0 = sqrtf(sj0), nj1 = sqrtf(sj1);
    float* s0 = sim + (size_t)(i0 + 2 * ty) * NN + j0 + 2 * tx;
    float* s1 = s0 + NN;
    s0[0] = acc00 / fmaxf(ni0 * nj0, CEPS) * invtemp;
    s0[1] = acc01 / fmaxf(ni0 * nj1, CEPS) * invtemp;
    s1[0] = acc10 / fmaxf(ni1 * nj0, CEPS) * invtemp;
    s1[1] = acc11 / fmaxf(ni1 * nj1, CEPS) * invtemp;
}

// one gram/transpose task (task in [0,1184)), 256-thread subgroup, my = 2176 floats LDS
__device__ void gram_task(const KParams& p, int task, int st, float* my) {
    if (task < 576) {
        gram_tile<DD>(p.visual, 10.f, p.simv, (task / 24) * 32, (task % 24) * 32, st, my,
                      my + 1088);
    } else if (task < 1152) {
        const int rem = task - 576;
        gram_tile<AA>(p.attribute, 10.f, p.sima, (rem / 24) * 32, (rem % 24) * 32, st, my,
                      my + 1088);
    } else {
        const int u = task - 1152;
        const float* S = (u >= 16) ? p.Wsn : p.Wvn;
        float* Dt = (u >= 16) ? p.WsnT : p.WvnT;
        const int tile = u & 15;
        const int c0 = (tile & 3) * 32, r0 = (tile >> 2) * 32;
        const int tx = st & 31, ty = st >> 5;
        #pragma unroll
        for (int rr = ty; rr < 32; rr += 8)
            my[rr * 33 + tx] = S[(size_t)(r0 + rr) * DD + c0 + tx];
        __syncthreads();
        #pragma unroll
        for (int rr = ty; rr < 32; rr += 8)
            Dt[(size_t)(c0 + rr) * DD + r0 + tx] = my[tx * 33 + rr];
    }
}

// block-wide softmax (512 threads) over a 768-float LDS buffer, in place.
__device__ void block_softmax768(float* buf, int tid, float* red) {
    const int w = tid >> 6, lane = tid & 63;
    float v0 = buf[tid];
    float v1 = (tid < NN - 512) ? buf[tid + 512] : -3.4e38f;
    float m = wave_max(fmaxf(v0, v1));
    if (lane == 0) red[w] = m;
    __syncthreads();
    m = red[0];
    #pragma unroll
    for (int i = 1; i < 8; ++i) m = fmaxf(m, red[i]);
    float e0 = __expf(v0 - m);
    float e1 = (tid < NN - 512) ? __expf(v1 - m) : 0.f;
    float sw = wave_sum(e0 + e1);
    if (lane == 0) red[8 + w] = sw;
    __syncthreads();
    float s = 0.f;
    #pragma unroll
    for (int i = 0; i < 8; ++i) s += red[8 + i];
    const float inv = 1.f / s;
    buf[tid] = e0 * inv;
    if (tid < NN - 512) buf[tid + 512] = e1 * inv;
    __syncthreads();
}

// ---------------- node update body (2 rows/task, 512 thr), LDS via overlay ----------------
template <bool SMEP, bool SMEX>
__device__ void node_body(const float* __restrict__ P, const float* __restrict__ EpSrc,
                          const float* __restrict__ ExSrc, const float* __restrict__ WT,
                          const float* __restrict__ b, const float* __restrict__ g,
                          const float* __restrict__ beta, float* __restrict__ out,
                          const float* __restrict__ W1e, short* __restrict__ outb,
                          float* __restrict__ cvec, int bid, int tid, float* smem) {
    float (*ep)[NN] = (float (*)[NN])smem;                       // 1536
    float (*ex)[NN] = (float (*)[NN])(smem + 2 * NN);            // 1536
    float (*pp)[2][DD] = (float (*)[2][DD])(smem + 4 * NN);      // 1024
    float (*xx)[2][DD] = (float (*)[2][DD])(smem + 4 * NN + 1024);
    float (*qs)[DD] = (float (*)[DD])(smem + 4 * NN + 2048);     // 256
    float (*tps)[2][DD] = (float (*)[2][DD])(smem + 4 * NN + 2304);  // 512
    float* red = smem + 4 * NN + 2816;                           // 16
    const int i0 = bid * 2;
    const int s = (tid >> 7) & 3, d = tid & 127;
    if (tid < 384) {  // two consecutive rows contiguous: 1536 floats = 384 float4
        ((float4*)ep)[tid] = ((const float4*)(EpSrc + (size_t)i0 * NN))[tid];
        ((float4*)ex)[tid] = ((const float4*)(ExSrc + (size_t)i0 * NN))[tid];
    }
    __syncthreads();
    if (SMEP) {
        block_softmax768(ep[0], tid, red);
        block_softmax768(ep[1], tid, red);
    }
    if (SMEX) {
        block_softmax768(ex[0], tid, red);
        block_softmax768(ex[1], tid, red);
    }
    float p0 = 0.f, x0 = 0.f, p1 = 0.f, x1 = 0.f;
    const int kb = s * 192;
    #pragma unroll 4
    for (int kk = 0; kk < 192; ++kk) {
        const int k = kb + kk;
        const float pv = P[(size_t)k * DD + d];
        p0 = fmaf(ep[0][k], pv, p0);
        x0 = fmaf(ex[0][k], pv, x0);
        p1 = fmaf(ep[1][k], pv, p1);
        x1 = fmaf(ex[1][k], pv, x1);
    }
    pp[s][0][d] = p0; xx[s][0][d] = x0;
    pp[s][1][d] = p1; xx[s][1][d] = x1;
    __syncthreads();
    const int rr = (tid >> 7) & 1;
    float preg = 0.f;
    if (tid < 256) {
        float p = pp[0][rr][d] + pp[1][rr][d] + pp[2][rr][d] + pp[3][rr][d];
        float x = xx[0][rr][d] + xx[1][rr][d] + xx[2][rr][d] + xx[3][rr][d];
        qs[rr][d] = p + x;
        preg = p;
    }
    __syncthreads();
    {
        const int sc = tid >> 8, rr2 = (tid >> 7) & 1;
        float t = (sc == 0) ? b[d] : 0.f;
        const int c0 = sc * 64;
        #pragma unroll 4
        for (int c = c0; c < c0 + 64; ++c) t = fmaf(qs[rr2][c], WT[(size_t)c * DD + d], t);
        tps[sc][rr2][d] = t;
    }
    __syncthreads();
    float tval = 0.f;
    if (tid < 256) tval = tps[0][rr][d] + tps[1][rr][d];
    float sm = wave_sum(tid < 256 ? tval : 0.f);
    if ((tid & 63) == 0) red[tid >> 6] = sm;
    __syncthreads();
    if (tid < 256) tval -= (red[2 * rr] + red[2 * rr + 1]) * (1.f / DD);
    float s2 = wave_sum(tid < 256 ? tval * tval : 0.f);
    if ((tid & 63) == 0) red[8 + (tid >> 6)] = s2;
    __syncthreads();
    if (tid < 256) {
        const float var = (red[8 + 2 * rr] + red[8 + 2 * rr + 1]) * (1.f / DD);
        const float ln = tval * rsqrtf(var + 1e-5f) * g[d] + beta[d];
        const float val = fmaxf(ln, 0.f) + preg;
        out[(size_t)(i0 + rr) * DD + d] = val;
        outb[(size_t)(i0 + rr) * DD + d] = (short)f2bf(val);
        qs[rr][d] = val;
    }
    __syncthreads();
    if (tid < 256) {
        const int row = tid >> 7, r = (tid >> 4) & 7, l16 = tid & 15;
        float ssum = 0.f;
        #pragma unroll
        for (int t = 0; t < 8; ++t) {
            const int k = l16 + 16 * t;
            const float pv = qs[row][k];
            ssum = fmaf(W1e[r * DD + k], pv * pv, ssum);
        }
        #pragma unroll
        for (int o = 8; o; o >>= 1) ssum += __shfl_down(ssum, o, 16);
        if (l16 == 0) cvec[(size_t)(i0 + row) * HH + r] = ssum;
    }
    __syncthreads();
}

// ---------------- edge logits body via MFMA + fused softmaxes, LDS via overlay ----------------
__device__ void edge_body(const float* __restrict__ PR, const short* __restrict__ PRb,
                          const float* __restrict__ cvec, const float* __restrict__ ELraw,
                          const float* __restrict__ W1, const float* __restrict__ b1,
                          const float* __restrict__ W2, const float* __restrict__ b2,
                          float invtemp, float* __restrict__ out, int bid, int tid, float* smem) {
    float (*pi)[DD] = (float (*)[DD])smem;            // 256
    float* w1s = smem + 256;                          // 1024
    short* a_sw = (short*)(smem + 1280);              // 2048 shorts = 1024 floats
    float (*Ls)[NN] = (float (*)[NN])(smem + 2304);   // 1536
    float (*Els)[NN] = (float (*)[NN])(smem + 3840);  // 1536
    float* red = smem + 5376;                         // 16
    const int i0 = bid * 2;
    const int lane = tid & 63, wave = tid >> 6;
    if (tid < 256) {
        pi[tid >> 7][tid & 127] = PR[(size_t)(i0 + (tid >> 7)) * DD + (tid & 127)];
        ((float4*)w1s)[tid] = ((const float4*)W1)[tid];
    }
    if (tid < 384)
        ((float4*)Els)[tid] = ((const float4*)(ELraw + (size_t)i0 * NN))[tid];
    __syncthreads();
    block_softmax768(Els[0], tid, red);
    block_softmax768(Els[1], tid, red);
    if (tid < 256) {  // A fragments: m = il*8+r, k = t*32 + q2*8 + e
        const int t = tid >> 6, m = lane & 15, q2 = lane >> 4;
        const int il = m >> 3, r = m & 7;
        const int kb = t * 32 + q2 * 8;
        s8b av;
        #pragma unroll
        for (int e = 0; e < 8; ++e)
            av[e] = (short)f2bf(pi[il][kb + e] * w1s[r * DD + kb + e]);
        *(s8b*)&a_sw[(t * 64 + lane) * 8] = av;
    }
    __syncthreads();
    s8b af[4];
    #pragma unroll
    for (int t = 0; t < 4; ++t) af[t] = *(const s8b*)&a_sw[(t * 64 + lane) * 8];
    const int q = lane >> 4, n = lane & 15;
    const int rbase = (q & 1) * 4;
    const int il = q >> 1;
    const float4 ci4 = *(const float4*)&cvec[(size_t)(i0 + il) * HH + rbase];
    const float4 b14 = *(const float4*)&b1[rbase];
    const float4 w24 = *(const float4*)&W2[rbase];
    const float b2s = b2[0];
    #pragma unroll
    for (int s = 0; s < 6; ++s) {
        const int j = wave * 96 + s * 16 + n;
        f4v acc = {0.f, 0.f, 0.f, 0.f};
        #pragma unroll
        for (int t = 0; t < 4; ++t) {
            const s8b bf = *(const s8b*)(PRb + (size_t)j * DD + t * 32 + q * 8);
            acc = __builtin_amdgcn_mfma_f32_16x16x32_bf16(af[t], bf, acc, 0, 0, 0);
        }
        const float4 cj = *(const float4*)&cvec[(size_t)j * HH + rbase];
        float z[4];
        z[0] = ci4.x + cj.x - 2.f * acc[0] + b14.x;
        z[1] = ci4.y + cj.y - 2.f * acc[1] + b14.y;
        z[2] = ci4.z + cj.z - 2.f * acc[2] + b14.z;
        z[3] = ci4.w + cj.w - 2.f * acc[3] + b14.w;
        float s1 = z[0] + z[1] + z[2] + z[3];
        float s2 = z[0] * z[0] + z[1] * z[1] + z[2] * z[2] + z[3] * z[3];
        s1 += __shfl_xor(s1, 16, 64);
        s2 += __shfl_xor(s2, 16, 64);
        const float mean = s1 * (1.f / HH);
        const float var = fmaxf(s2 * (1.f / HH) - mean * mean, 0.f);
        const float istd = rsqrtf(var + 1e-5f);
        float a2 = 0.f;
        a2 = fmaf(fmaxf((z[0] - mean) * istd, 0.f), w24.x, a2);
        a2 = fmaf(fmaxf((z[1] - mean) * istd, 0.f), w24.y, a2);
        a2 = fmaf(fmaxf((z[2] - mean) * istd, 0.f), w24.z, a2);
        a2 = fmaf(fmaxf((z[3] - mean) * istd, 0.f), w24.w, a2);
        a2 += __shfl_xor(a2, 16, 64);
        const float tv = tanhf(a2 + b2s);
        const float lv = Els[il][j];
        if ((q & 1) == 0) Ls[il][j] = tv * (lv + CEPS) * invtemp;
    }
    __syncthreads();
    block_softmax768(Ls[0], tid, red);
    block_softmax768(Ls[1], tid, red);
    float* d0 = out + (size_t)i0 * NN;
    float* d1 = out + (size_t)(i0 + 1) * NN;
    d0[tid] = Ls[0][tid];
    d1[tid] = Ls[1][tid];
    if (tid < NN - 512) {
        d0[tid + 512] = Ls[0][tid + 512];
        d1[tid + 512] = Ls[1][tid + 512];
    }
    __syncthreads();
}

// ---------------- fallback path: 5 separate kernels (verified round-3 behavior) ------------
__global__ __launch_bounds__(256) void gram_prep_kernel(KParams p) {
    __shared__ __align__(16) float smem[2176];
    gram_task(p, blockIdx.x, threadIdx.x, smem);
}
template <bool SMEP, bool SMEX>
__global__ __launch_bounds__(512) void node_kernel(const float* P, const float* EpSrc,
                                                   const float* ExSrc, const float* WT,
                                                   const float* b, const float* g,
                                                   const float* beta, float* out,
                                                   const float* W1e, short* outb, float* cvec) {
    __shared__ __align__(16) float smem[SMEM_F];
    node_body<SMEP, SMEX>(P, EpSrc, ExSrc, WT, b, g, beta, out, W1e, outb, cvec, blockIdx.x,
                          threadIdx.x, smem);
}
__global__ __launch_bounds__(512) void edge_kernel(const float* PR, const short* PRb,
                                                   const float* cvec, const float* ELraw,
                                                   const float* W1, const float* b1,
                                                   const float* W2, const float* b2,
                                                   float invtemp, float* out) {
    __shared__ __align__(16) float smem[SMEM_F];
    edge_body(PR, PRb, cvec, ELraw, W1, b1, W2, b2, invtemp, out, blockIdx.x, threadIdx.x, smem);
}

// ---------------- single cooperative kernel: gram -> node1 -> edge1 -> node2 -> edge2 --------
__global__ __launch_bounds__(512, 4) void fused_all(KParams p) {
    cg::grid_group grid = cg::this_grid();
    __shared__ __align__(16) float smem[SMEM_F];
    const int tid = threadIdx.x;
    const int bid = blockIdx.x;
    const int nb = gridDim.x;

    // phase 0: 592 paired gram/transpose tasks (both 256-thread halves in the same class).
    {
        const int half = tid >> 8;
        const int st = tid & 255;
        float* my = smem + half * 2176;
        for (int pr = bid; pr < 592; pr += nb) {
            gram_task(p, pr * 2 + half, st, my);
            __syncthreads();
        }
    }
    __threadfence();
    grid.sync();
    // phase 1: node1  vp = f(visual, ep=softmax(simv rows), ex=softmax(sima rows))
    for (int t = bid; t < 384; t += nb)
        node_body<true, true>(p.visual, p.simv, p.sima, p.WvnT, p.bvn, p.gvn, p.betavn, p.vp,
                              p.Wve1, p.vpb, p.cvec1, t, tid, smem);
    __threadfence();
    grid.sync();
    // phase 2: edge1  ve2 = softmax(logits(vp) * (softmax(simv rows)+eps) / VTEMP)
    for (int t = bid; t < 384; t += nb)
        edge_body(p.vp, p.vpb, p.cvec1, p.simv, p.Wve1, p.bve1, p.Wve2, p.bve2, 0.1f, p.ve2, t,
                  tid, smem);
    __threadfence();
    grid.sync();
    // phase 3: node2  sp = f(semantic, ep=softmax(sima rows), ex=ve2 rows)
    for (int t = bid; t < 384; t += nb)
        node_body<true, false>(p.semantic, p.sima, p.ve2, p.WsnT, p.bsn, p.gsn, p.betasn, p.sp,
                               p.Wse1, p.spb, p.cvec2, t, tid, smem);
    __threadfence();
    grid.sync();
    // phase 4: edge2  se2 = softmax(logits(sp) * (softmax(sima rows)+eps) / STEMP)
    for (int t = bid; t < 384; t += nb)
        edge_body(p.sp, p.spb, p.cvec2, p.sima, p.Wse1, p.bse1, p.Wse2, p.bse2, 0.1f, p.se2, t,
                  tid, smem);
}

extern "C" void kernel_launch(void* const* d_in, const int* in_sizes, int n_in, void* d_out,
                              int out_size, void* d_ws, size_t ws_size, hipStream_t stream) {
    KParams kp;
    kp.visual    = (const float*)d_in[0];
    kp.semantic  = (const float*)d_in[1];
    kp.attribute = (const float*)d_in[2];
    kp.Wvn  = (const float*)d_in[3];
    kp.bvn  = (const float*)d_in[4];
    kp.gvn  = (const float*)d_in[5];
    kp.betavn = (const float*)d_in[6];
    kp.Wve1 = (const float*)d_in[7];
    kp.bve1 = (const float*)d_in[8];
    kp.Wve2 = (const float*)d_in[9];
    kp.bve2 = (const float*)d_in[10];
    kp.Wsn  = (const float*)d_in[11];
    kp.bsn  = (const float*)d_in[12];
    kp.gsn  = (const float*)d_in[13];
    kp.betasn = (const float*)d_in[14];
    kp.Wse1 = (const float*)d_in[15];
    kp.bse1 = (const float*)d_in[16];
    kp.Wse2 = (const float*)d_in[17];
    kp.bse2 = (const float*)d_in[18];

    float* out = (float*)d_out;
    kp.vp  = out;              // 768*128
    kp.sp  = out + 98304;      // 768*128
    kp.ve2 = out + 196608;     // 768*768
    kp.se2 = out + 786432;     // 768*768

    float* ws = (float*)d_ws;
    kp.simv  = ws;             // 768*768 raw pre-scaled logits (x10)
    kp.sima  = ws + 589824;
    kp.WvnT  = ws + 2949120;   // 128*128
    kp.WsnT  = ws + 2965504;
    kp.cvec1 = ws + 2981888;   // 768*8
    kp.cvec2 = ws + 2988032;
    kp.vpb   = (short*)(ws + 2994176);  // 768*128 bf16
    kp.spb   = (short*)(ws + 3043328);

    static int coop_state = 0;  // 0 = unknown, 1 = works, -1 = banned
    static int coop_grid = 0;

    bool did_coop = false;
    if (coop_state >= 0) {
        if (coop_grid == 0) {
            int bpc = 0;
            hipError_t qe = hipOccupancyMaxActiveBlocksPerMultiprocessor(
                &bpc, (const void*)fused_all, 512, 0);
            if (qe != hipSuccess || bpc < 1) {
                coop_state = -1;
            } else {
                coop_grid = bpc * 256;
                if (coop_grid > 512) coop_grid = 512;
            }
        }
        if (coop_state >= 0) {
            void* args[] = {(void*)&kp};
            hipError_t le = hipLaunchCooperativeKernel((const void*)fused_all,
                                                       dim3(coop_grid), dim3(512), args, 0,
                                                       stream);
            if (le == hipSuccess) {
                coop_state = 1;
                did_coop = true;
            } else {
                coop_state = -1;  // rejected (e.g. too large / capture unsupported) -> fallback
            }
        }
    }
    if (!did_coop) {
        gram_prep_kernel<<<1184, 256, 0, stream>>>(kp);
        node_kernel<true, true><<<NN / 2, 512, 0, stream>>>(kp.visual, kp.simv, kp.sima,
                                                            kp.WvnT, kp.bvn, kp.gvn, kp.betavn,
                                                            kp.vp, kp.Wve1, kp.vpb, kp.cvec1);
        edge_kernel<<<NN / 2, 512, 0, stream>>>(kp.vp, kp.vpb, kp.cvec1, kp.simv, kp.Wve1,
                                                kp.bve1, kp.Wve2, kp.bve2, 0.1f, kp.ve2);
        node_kernel<true, false><<<NN / 2, 512, 0, stream>>>(kp.semantic, kp.sima, kp.ve2,
                                                             kp.WsnT, kp.bsn, kp.gsn, kp.betasn,
                                                             kp.sp, kp.Wse1, kp.spb, kp.cvec2);
        edge_kernel<<<NN / 2, 512, 0, stream>>>(kp.sp, kp.spb, kp.cvec2, kp.sima, kp.Wse1,
                                                kp.bse1, kp.Wse2, kp.bse2, 0.1f, kp.se2);
    }
}

// Round 7
// 190.449 us; speedup vs baseline: 1.2315x; 1.2315x over previous
//
#include <hip/hip_runtime.h>
#include <math.h>

#define NN 768
#define DD 128
#define AA 312
#define HH 8
#define CEPS 1e-8f
#define SMEM_F 5920

typedef __attribute__((ext_vector_type(8))) short s8b;   // 8 x bf16
typedef __attribute__((ext_vector_type(4))) float f4v;   // MFMA C/D

__device__ __forceinline__ float wave_sum(float v) {
    #pragma unroll
    for (int o = 32; o; o >>= 1) v += __shfl_down(v, o, 64);
    return v;
}
__device__ __forceinline__ float wave_max(float v) {
    #pragma unroll
    for (int o = 32; o; o >>= 1) v = fmaxf(v, __shfl_down(v, o, 64));
    return v;
}
__device__ __forceinline__ unsigned short f2bf(float f) {
    unsigned u = __float_as_uint(f);
    u += 0x7FFFu + ((u >> 16) & 1u);
    return (unsigned short)(u >> 16);
}

struct KParams {
    const float *visual, *semantic, *attribute;
    const float *Wvn, *bvn, *gvn, *betavn, *Wve1, *bve1, *Wve2, *bve2;
    const float *Wsn, *bsn, *gsn, *betasn, *Wse1, *bse1, *Wse2, *bse2;
    float *vp, *sp, *ve2, *se2;
    float *simv, *sima, *WvnT, *WsnT, *cvec1, *cvec2;
    float *nrmv, *nrma;
    short *vpb, *spb;
};

// ---------------- K1: MFMA bf16x2-split gram (raw G) + diag norms + W transposes -----------
// G = M M^T computed as Ahi*Bhi + Ahi*Blo + Alo*Bhi (bf16 split, fp32 accum).
// 64x64 tile/block, 256 thr = 4 waves (wave w owns i-strip w*16..w*16+15).
__global__ __launch_bounds__(256) void gram_mfma_kernel(KParams p) {
    __shared__ __align__(16) unsigned short AH[64 * 40];
    __shared__ __align__(16) unsigned short AL[64 * 40];
    __shared__ __align__(16) unsigned short BH[64 * 40];
    __shared__ __align__(16) unsigned short BL[64 * 40];
    const int task = blockIdx.x;
    const int tid = threadIdx.x;
    if (task < 288) {
        const bool isv = (task < 144);
        const int tt = isv ? task : task - 144;
        const int bi = tt / 12, bj = tt % 12;
        const float* M = isv ? p.visual : p.attribute;
        float* G = isv ? p.simv : p.sima;
        float* nrm = isv ? p.nrmv : p.nrma;
        const int K = isv ? DD : AA;
        const int i0 = bi * 64, j0 = bj * 64;
        const int w = tid >> 6, lane = tid & 63;
        const int m = lane & 15, q = lane >> 4;
        f4v acc[4] = {{0.f, 0.f, 0.f, 0.f}, {0.f, 0.f, 0.f, 0.f},
                      {0.f, 0.f, 0.f, 0.f}, {0.f, 0.f, 0.f, 0.f}};
        const int nchunk = (K + 31) >> 5;
        const int srow = tid >> 2, sq = (tid & 3) * 8;
        for (int c = 0; c < nchunk; ++c) {
            const int kc = c * 32;
            __syncthreads();
            #pragma unroll
            for (int h = 0; h < 2; ++h) {
                const int col = sq + h * 4;
                float4 a = {0.f, 0.f, 0.f, 0.f}, b = {0.f, 0.f, 0.f, 0.f};
                if (kc + col + 4 <= K) {
                    a = *(const float4*)(M + (size_t)(i0 + srow) * K + kc + col);
                    b = *(const float4*)(M + (size_t)(j0 + srow) * K + kc + col);
                }
                const float av[4] = {a.x, a.y, a.z, a.w};
                const float bv[4] = {b.x, b.y, b.z, b.w};
                #pragma unroll
                for (int e = 0; e < 4; ++e) {
                    const unsigned short ah = f2bf(av[e]);
                    const float ahf = __uint_as_float((unsigned)ah << 16);
                    const unsigned short al = f2bf(av[e] - ahf);
                    const unsigned short bh = f2bf(bv[e]);
                    const float bhf = __uint_as_float((unsigned)bh << 16);
                    const unsigned short bl = f2bf(bv[e] - bhf);
                    AH[srow * 40 + col + e] = ah;
                    AL[srow * 40 + col + e] = al;
                    BH[srow * 40 + col + e] = bh;
                    BL[srow * 40 + col + e] = bl;
                }
            }
            __syncthreads();
            const s8b ah8 = *(const s8b*)&AH[(w * 16 + m) * 40 + q * 8];
            const s8b al8 = *(const s8b*)&AL[(w * 16 + m) * 40 + q * 8];
            #pragma unroll
            for (int jt = 0; jt < 4; ++jt) {
                const s8b bh8 = *(const s8b*)&BH[(jt * 16 + m) * 40 + q * 8];
                const s8b bl8 = *(const s8b*)&BL[(jt * 16 + m) * 40 + q * 8];
                acc[jt] = __builtin_amdgcn_mfma_f32_16x16x32_bf16(ah8, bh8, acc[jt], 0, 0, 0);
                acc[jt] = __builtin_amdgcn_mfma_f32_16x16x32_bf16(ah8, bl8, acc[jt], 0, 0, 0);
                acc[jt] = __builtin_amdgcn_mfma_f32_16x16x32_bf16(al8, bh8, acc[jt], 0, 0, 0);
            }
        }
        // C/D layout: row = q*4 + reg (within wave's 16-strip), col = m.
        #pragma unroll
        for (int jt = 0; jt < 4; ++jt) {
            #pragma unroll
            for (int r = 0; r < 4; ++r) {
                G[(size_t)(i0 + w * 16 + q * 4 + r) * NN + j0 + jt * 16 + m] = acc[jt][r];
                if (bi == bj && jt == w && m == q * 4 + r)
                    nrm[i0 + w * 16 + m] = sqrtf(fmaxf(acc[jt][r], 0.f));
            }
        }
    } else {
        float* smem = (float*)AH;  // 4224 B needed <= 5120 B
        const int u = task - 288;
        const float* S = (u >= 16) ? p.Wsn : p.Wvn;
        float* Dt = (u >= 16) ? p.WsnT : p.WvnT;
        const int tile = u & 15;
        const int c0 = (tile & 3) * 32, r0 = (tile >> 2) * 32;
        const int tx = tid & 31, ty = tid >> 5;
        #pragma unroll
        for (int rr = ty; rr < 32; rr += 8)
            smem[rr * 33 + tx] = S[(size_t)(r0 + rr) * DD + c0 + tx];
        __syncthreads();
        #pragma unroll
        for (int rr = ty; rr < 32; rr += 8)
            Dt[(size_t)(c0 + rr) * DD + r0 + tx] = smem[tx * 33 + rr];
    }
}

// block-wide softmax (512 threads) over a 768-float LDS buffer, in place.
__device__ void block_softmax768(float* buf, int tid, float* red) {
    const int w = tid >> 6, lane = tid & 63;
    float v0 = buf[tid];
    float v1 = (tid < NN - 512) ? buf[tid + 512] : -3.4e38f;
    float m = wave_max(fmaxf(v0, v1));
    if (lane == 0) red[w] = m;
    __syncthreads();
    m = red[0];
    #pragma unroll
    for (int i = 1; i < 8; ++i) m = fmaxf(m, red[i]);
    float e0 = __expf(v0 - m);
    float e1 = (tid < NN - 512) ? __expf(v1 - m) : 0.f;
    float sw = wave_sum(e0 + e1);
    if (lane == 0) red[8 + w] = sw;
    __syncthreads();
    float s = 0.f;
    #pragma unroll
    for (int i = 0; i < 8; ++i) s += red[8 + i];
    const float inv = 1.f / s;
    buf[tid] = e0 * inv;
    if (tid < NN - 512) buf[tid + 512] = e1 * inv;
    __syncthreads();
}

// normalize 2 raw gram rows in LDS: val = G*10/max(ni*nj, eps)
__device__ void norm_rows(float (*buf)[NN], const float* __restrict__ nrm, int i0, int tid) {
    const float n0 = nrm[i0], n1 = nrm[i0 + 1];
    for (int k = tid; k < NN; k += 512) {
        const float nj = nrm[k];
        buf[0][k] = buf[0][k] * 10.f / fmaxf(n0 * nj, CEPS);
        buf[1][k] = buf[1][k] * 10.f / fmaxf(n1 * nj, CEPS);
    }
}

// ---------------- K2/K4: node update (2 rows/block, 512 thr) ----------------
// SMEP/SMEX: source rows are RAW gram -> normalize + softmax in LDS here.
template <bool SMEP, bool SMEX>
__global__ __launch_bounds__(512) void node_kernel(
    const float* __restrict__ P, const float* __restrict__ EpSrc, const float* __restrict__ ExSrc,
    const float* __restrict__ nrmP, const float* __restrict__ nrmX,
    const float* __restrict__ WT, const float* __restrict__ b, const float* __restrict__ g,
    const float* __restrict__ beta, float* __restrict__ out, const float* __restrict__ W1e,
    short* __restrict__ outb, float* __restrict__ cvec) {
    __shared__ __align__(16) float ep[2][NN], ex[2][NN];
    __shared__ __align__(16) float pp[4][2][DD], xx[4][2][DD];
    __shared__ __align__(16) float qs[2][DD], tps[2][2][DD];
    __shared__ float red[16];
    const int i0 = blockIdx.x * 2;
    const int tid = threadIdx.x;
    const int s = (tid >> 7) & 3, d = tid & 127;
    if (tid < 384) {  // two consecutive rows contiguous: 1536 floats = 384 float4
        ((float4*)ep)[tid] = ((const float4*)(EpSrc + (size_t)i0 * NN))[tid];
        ((float4*)ex)[tid] = ((const float4*)(ExSrc + (size_t)i0 * NN))[tid];
    }
    __syncthreads();
    if (SMEP) {
        norm_rows(ep, nrmP, i0, tid);
        block_softmax768(ep[0], tid, red);
        block_softmax768(ep[1], tid, red);
    }
    if (SMEX) {
        norm_rows(ex, nrmX, i0, tid);
        block_softmax768(ex[0], tid, red);
        block_softmax768(ex[1], tid, red);
    }
    float p0 = 0.f, x0 = 0.f, p1 = 0.f, x1 = 0.f;
    const int kb = s * 192;
    #pragma unroll 4
    for (int kk = 0; kk < 192; ++kk) {
        const int k = kb + kk;
        const float pv = P[(size_t)k * DD + d];
        p0 = fmaf(ep[0][k], pv, p0);
        x0 = fmaf(ex[0][k], pv, x0);
        p1 = fmaf(ep[1][k], pv, p1);
        x1 = fmaf(ex[1][k], pv, x1);
    }
    pp[s][0][d] = p0; xx[s][0][d] = x0;
    pp[s][1][d] = p1; xx[s][1][d] = x1;
    __syncthreads();
    const int rr = (tid >> 7) & 1;
    float preg = 0.f;
    if (tid < 256) {
        float p = pp[0][rr][d] + pp[1][rr][d] + pp[2][rr][d] + pp[3][rr][d];
        float x = xx[0][rr][d] + xx[1][rr][d] + xx[2][rr][d] + xx[3][rr][d];
        qs[rr][d] = p + x;
        preg = p;
    }
    __syncthreads();
    {
        const int sc = tid >> 8, rr2 = (tid >> 7) & 1;
        float t = (sc == 0) ? b[d] : 0.f;
        const int c0 = sc * 64;
        #pragma unroll 4
        for (int c = c0; c < c0 + 64; ++c) t = fmaf(qs[rr2][c], WT[(size_t)c * DD + d], t);
        tps[sc][rr2][d] = t;
    }
    __syncthreads();
    float tval = 0.f;
    if (tid < 256) tval = tps[0][rr][d] + tps[1][rr][d];
    float sm = wave_sum(tid < 256 ? tval : 0.f);
    if ((tid & 63) == 0) red[tid >> 6] = sm;
    __syncthreads();
    if (tid < 256) tval -= (red[2 * rr] + red[2 * rr + 1]) * (1.f / DD);
    float s2 = wave_sum(tid < 256 ? tval * tval : 0.f);
    if ((tid & 63) == 0) red[8 + (tid >> 6)] = s2;
    __syncthreads();
    if (tid < 256) {
        const float var = (red[8 + 2 * rr] + red[8 + 2 * rr + 1]) * (1.f / DD);
        const float ln = tval * rsqrtf(var + 1e-5f) * g[d] + beta[d];
        const float val = fmaxf(ln, 0.f) + preg;
        out[(size_t)(i0 + rr) * DD + d] = val;
        outb[(size_t)(i0 + rr) * DD + d] = (short)f2bf(val);
        qs[rr][d] = val;
    }
    __syncthreads();
    if (tid < 256) {
        const int row = tid >> 7, r = (tid >> 4) & 7, l16 = tid & 15;
        float ssum = 0.f;
        #pragma unroll
        for (int t = 0; t < 8; ++t) {
            const int k = l16 + 16 * t;
            const float pv = qs[row][k];
            ssum = fmaf(W1e[r * DD + k], pv * pv, ssum);
        }
        #pragma unroll
        for (int o = 8; o; o >>= 1) ssum += __shfl_down(ssum, o, 16);
        if (l16 == 0) cvec[(size_t)(i0 + row) * HH + r] = ssum;
    }
}

// ---------------- K3/K5: edge logits via MFMA + fused Elast(norm+softmax) + out softmax -----
__global__ __launch_bounds__(512) void edge_kernel(
    const float* __restrict__ PR, const short* __restrict__ PRb, const float* __restrict__ cvec,
    const float* __restrict__ ELraw, const float* __restrict__ nrmE,
    const float* __restrict__ W1, const float* __restrict__ b1, const float* __restrict__ W2,
    const float* __restrict__ b2, float invtemp, float* __restrict__ out) {
    __shared__ __align__(16) float pi[2][DD];
    __shared__ __align__(16) float w1s[HH * DD];
    __shared__ __align__(16) short a_sw[4 * 64 * 8];
    __shared__ __align__(16) float Ls[2][NN];
    __shared__ __align__(16) float Els[2][NN];
    __shared__ float red[16];
    const int i0 = blockIdx.x * 2;
    const int tid = threadIdx.x;
    const int lane = tid & 63, wave = tid >> 6;
    if (tid < 256) {
        pi[tid >> 7][tid & 127] = PR[(size_t)(i0 + (tid >> 7)) * DD + (tid & 127)];
        ((float4*)w1s)[tid] = ((const float4*)W1)[tid];
    }
    if (tid < 384)
        ((float4*)Els)[tid] = ((const float4*)(ELraw + (size_t)i0 * NN))[tid];
    __syncthreads();
    norm_rows(Els, nrmE, i0, tid);
    block_softmax768(Els[0], tid, red);
    block_softmax768(Els[1], tid, red);
    if (tid < 256) {  // A fragments: m = il*8+r, k = t*32 + q2*8 + e
        const int t = tid >> 6, m = lane & 15, q2 = lane >> 4;
        const int il = m >> 3, r = m & 7;
        const int kb = t * 32 + q2 * 8;
        s8b av;
        #pragma unroll
        for (int e = 0; e < 8; ++e)
            av[e] = (short)f2bf(pi[il][kb + e] * w1s[r * DD + kb + e]);
        *(s8b*)&a_sw[(t * 64 + lane) * 8] = av;
    }
    __syncthreads();
    s8b af[4];
    #pragma unroll
    for (int t = 0; t < 4; ++t) af[t] = *(const s8b*)&a_sw[(t * 64 + lane) * 8];
    const int q = lane >> 4, n = lane & 15;
    const int rbase = (q & 1) * 4;
    const int il = q >> 1;
    const float4 ci4 = *(const float4*)&cvec[(size_t)(i0 + il) * HH + rbase];
    const float4 b14 = *(const float4*)&b1[rbase];
    const float4 w24 = *(const float4*)&W2[rbase];
    const float b2s = b2[0];
    #pragma unroll
    for (int s = 0; s < 6; ++s) {
        const int j = wave * 96 + s * 16 + n;
        f4v acc = {0.f, 0.f, 0.f, 0.f};
        #pragma unroll
        for (int t = 0; t < 4; ++t) {
            const s8b bf = *(const s8b*)(PRb + (size_t)j * DD + t * 32 + q * 8);
            acc = __builtin_amdgcn_mfma_f32_16x16x32_bf16(af[t], bf, acc, 0, 0, 0);
        }
        const float4 cj = *(const float4*)&cvec[(size_t)j * HH + rbase];
        float z[4];
        z[0] = ci4.x + cj.x - 2.f * acc[0] + b14.x;
        z[1] = ci4.y + cj.y - 2.f * acc[1] + b14.y;
        z[2] = ci4.z + cj.z - 2.f * acc[2] + b14.z;
        z[3] = ci4.w + cj.w - 2.f * acc[3] + b14.w;
        float s1 = z[0] + z[1] + z[2] + z[3];
        float s2 = z[0] * z[0] + z[1] * z[1] + z[2] * z[2] + z[3] * z[3];
        s1 += __shfl_xor(s1, 16, 64);
        s2 += __shfl_xor(s2, 16, 64);
        const float mean = s1 * (1.f / HH);
        const float var = fmaxf(s2 * (1.f / HH) - mean * mean, 0.f);
        const float istd = rsqrtf(var + 1e-5f);
        float a2 = 0.f;
        a2 = fmaf(fmaxf((z[0] - mean) * istd, 0.f), w24.x, a2);
        a2 = fmaf(fmaxf((z[1] - mean) * istd, 0.f), w24.y, a2);
        a2 = fmaf(fmaxf((z[2] - mean) * istd, 0.f), w24.z, a2);
        a2 = fmaf(fmaxf((z[3] - mean) * istd, 0.f), w24.w, a2);
        a2 += __shfl_xor(a2, 16, 64);
        const float tv = tanhf(a2 + b2s);
        const float lv = Els[il][j];
        if ((q & 1) == 0) Ls[il][j] = tv * (lv + CEPS) * invtemp;
    }
    __syncthreads();
    block_softmax768(Ls[0], tid, red);
    block_softmax768(Ls[1], tid, red);
    float* d0 = out + (size_t)i0 * NN;
    float* d1 = out + (size_t)(i0 + 1) * NN;
    d0[tid] = Ls[0][tid];
    d1[tid] = Ls[1][tid];
    if (tid < NN - 512) {
        d0[tid + 512] = Ls[0][tid + 512];
        d1[tid + 512] = Ls[1][tid + 512];
    }
}

extern "C" void kernel_launch(void* const* d_in, const int* in_sizes, int n_in, void* d_out,
                              int out_size, void* d_ws, size_t ws_size, hipStream_t stream) {
    KParams kp;
    kp.visual    = (const float*)d_in[0];
    kp.semantic  = (const float*)d_in[1];
    kp.attribute = (const float*)d_in[2];
    kp.Wvn  = (const float*)d_in[3];
    kp.bvn  = (const float*)d_in[4];
    kp.gvn  = (const float*)d_in[5];
    kp.betavn = (const float*)d_in[6];
    kp.Wve1 = (const float*)d_in[7];
    kp.bve1 = (const float*)d_in[8];
    kp.Wve2 = (const float*)d_in[9];
    kp.bve2 = (const float*)d_in[10];
    kp.Wsn  = (const float*)d_in[11];
    kp.bsn  = (const float*)d_in[12];
    kp.gsn  = (const float*)d_in[13];
    kp.betasn = (const float*)d_in[14];
    kp.Wse1 = (const float*)d_in[15];
    kp.bse1 = (const float*)d_in[16];
    kp.Wse2 = (const float*)d_in[17];
    kp.bse2 = (const float*)d_in[18];

    float* out = (float*)d_out;
    kp.vp  = out;              // 768*128
    kp.sp  = out + 98304;      // 768*128
    kp.ve2 = out + 196608;     // 768*768
    kp.se2 = out + 786432;     // 768*768

    float* ws = (float*)d_ws;
    kp.simv  = ws;             // 768*768 RAW gram
    kp.sima  = ws + 589824;
    kp.WvnT  = ws + 2949120;   // 128*128
    kp.WsnT  = ws + 2965504;
    kp.cvec1 = ws + 2981888;   // 768*8
    kp.cvec2 = ws + 2988032;
    kp.vpb   = (short*)(ws + 2994176);  // 768*128 bf16 (49152 floats)
    kp.spb   = (short*)(ws + 3043328);
    kp.nrmv  = ws + 3092480;   // 768
    kp.nrma  = ws + 3093248;   // 768

    gram_mfma_kernel<<<320, 256, 0, stream>>>(kp);
    // node1: vp = f(visual, ep=softmax(norm(simv rows)), ex=softmax(norm(sima rows)))
    node_kernel<true, true><<<NN / 2, 512, 0, stream>>>(
        kp.visual, kp.simv, kp.sima, kp.nrmv, kp.nrma, kp.WvnT, kp.bvn, kp.gvn, kp.betavn,
        kp.vp, kp.Wve1, kp.vpb, kp.cvec1);
    // edge1: ve2 = softmax(logits(vp) * (softmax(norm(simv rows))+eps) / VTEMP)
    edge_kernel<<<NN / 2, 512, 0, stream>>>(kp.vp, kp.vpb, kp.cvec1, kp.simv, kp.nrmv, kp.Wve1,
                                            kp.bve1, kp.Wve2, kp.bve2, 0.1f, kp.ve2);
    // node2: sp = f(semantic, ep=softmax(norm(sima rows)), ex=ve2 rows)
    node_kernel<true, false><<<NN / 2, 512, 0, stream>>>(
        kp.semantic, kp.sima, kp.ve2, kp.nrma, nullptr, kp.WsnT, kp.bsn, kp.gsn, kp.betasn,
        kp.sp, kp.Wse1, kp.spb, kp.cvec2);
    // edge2: se2 = softmax(logits(sp) * (softmax(norm(sima rows))+eps) / STEMP)
    edge_kernel<<<NN / 2, 512, 0, stream>>>(kp.sp, kp.spb, kp.cvec2, kp.sima, kp.nrma, kp.Wse1,
                                            kp.bse1, kp.Wse2, kp.bse2, 0.1f, kp.se2);
}

// Round 8
// 183.979 us; speedup vs baseline: 1.2748x; 1.0352x over previous
//
#include <hip/hip_runtime.h>
#include <math.h>

#define NN 768
#define DD 128
#define AA 312
#define HH 8
#define CEPS 1e-8f

typedef __attribute__((ext_vector_type(8))) short s8b;   // 8 x bf16
typedef __attribute__((ext_vector_type(4))) float f4v;   // MFMA C/D

__device__ __forceinline__ float wave_sum(float v) {
    #pragma unroll
    for (int o = 32; o; o >>= 1) v += __shfl_down(v, o, 64);
    return v;
}
__device__ __forceinline__ float wave_max(float v) {
    #pragma unroll
    for (int o = 32; o; o >>= 1) v = fmaxf(v, __shfl_down(v, o, 64));
    return v;
}
__device__ __forceinline__ unsigned short f2bf(float f) {
    unsigned u = __float_as_uint(f);
    u += 0x7FFFu + ((u >> 16) & 1u);
    return (unsigned short)(u >> 16);
}

struct KParams {
    const float *visual, *semantic, *attribute;
    const float *Wvn, *bvn, *gvn, *betavn, *Wve1, *bve1, *Wve2, *bve2;
    const float *Wsn, *bsn, *gsn, *betasn, *Wse1, *bse1, *Wse2, *bse2;
    float *vp, *sp, *ve2, *se2;
    float *simv, *sima, *WvnT, *WsnT, *cvec1, *cvec2;
    float *nrmv, *nrma, *ve, *se;
    short *vpb, *spb;
};

// ---------------- K1: MFMA bf16x2-split gram (raw G) + diag norms + W transposes -----------
// G = M M^T computed as Ahi*Bhi + Ahi*Blo + Alo*Bhi (bf16 split, fp32 accum).
// 64x64 tile/block, 256 thr = 4 waves (wave w owns i-strip w*16..w*16+15).
__global__ __launch_bounds__(256) void gram_mfma_kernel(KParams p) {
    __shared__ __align__(16) unsigned short AH[64 * 40];
    __shared__ __align__(16) unsigned short AL[64 * 40];
    __shared__ __align__(16) unsigned short BH[64 * 40];
    __shared__ __align__(16) unsigned short BL[64 * 40];
    const int task = blockIdx.x;
    const int tid = threadIdx.x;
    if (task < 288) {
        const bool isv = (task < 144);
        const int tt = isv ? task : task - 144;
        const int bi = tt / 12, bj = tt % 12;
        const float* M = isv ? p.visual : p.attribute;
        float* G = isv ? p.simv : p.sima;
        float* nrm = isv ? p.nrmv : p.nrma;
        const int K = isv ? DD : AA;
        const int i0 = bi * 64, j0 = bj * 64;
        const int w = tid >> 6, lane = tid & 63;
        const int m = lane & 15, q = lane >> 4;
        f4v acc[4] = {{0.f, 0.f, 0.f, 0.f}, {0.f, 0.f, 0.f, 0.f},
                      {0.f, 0.f, 0.f, 0.f}, {0.f, 0.f, 0.f, 0.f}};
        const int nchunk = (K + 31) >> 5;
        const int srow = tid >> 2, sq = (tid & 3) * 8;
        for (int c = 0; c < nchunk; ++c) {
            const int kc = c * 32;
            __syncthreads();
            #pragma unroll
            for (int h = 0; h < 2; ++h) {
                const int col = sq + h * 4;
                float4 a = {0.f, 0.f, 0.f, 0.f}, b = {0.f, 0.f, 0.f, 0.f};
                if (kc + col + 4 <= K) {
                    a = *(const float4*)(M + (size_t)(i0 + srow) * K + kc + col);
                    b = *(const float4*)(M + (size_t)(j0 + srow) * K + kc + col);
                }
                const float av[4] = {a.x, a.y, a.z, a.w};
                const float bv[4] = {b.x, b.y, b.z, b.w};
                #pragma unroll
                for (int e = 0; e < 4; ++e) {
                    const unsigned short ah = f2bf(av[e]);
                    const float ahf = __uint_as_float((unsigned)ah << 16);
                    const unsigned short al = f2bf(av[e] - ahf);
                    const unsigned short bh = f2bf(bv[e]);
                    const float bhf = __uint_as_float((unsigned)bh << 16);
                    const unsigned short bl = f2bf(bv[e] - bhf);
                    AH[srow * 40 + col + e] = ah;
                    AL[srow * 40 + col + e] = al;
                    BH[srow * 40 + col + e] = bh;
                    BL[srow * 40 + col + e] = bl;
                }
            }
            __syncthreads();
            const s8b ah8 = *(const s8b*)&AH[(w * 16 + m) * 40 + q * 8];
            const s8b al8 = *(const s8b*)&AL[(w * 16 + m) * 40 + q * 8];
            #pragma unroll
            for (int jt = 0; jt < 4; ++jt) {
                const s8b bh8 = *(const s8b*)&BH[(jt * 16 + m) * 40 + q * 8];
                const s8b bl8 = *(const s8b*)&BL[(jt * 16 + m) * 40 + q * 8];
                acc[jt] = __builtin_amdgcn_mfma_f32_16x16x32_bf16(ah8, bh8, acc[jt], 0, 0, 0);
                acc[jt] = __builtin_amdgcn_mfma_f32_16x16x32_bf16(ah8, bl8, acc[jt], 0, 0, 0);
                acc[jt] = __builtin_amdgcn_mfma_f32_16x16x32_bf16(al8, bh8, acc[jt], 0, 0, 0);
            }
        }
        // C/D layout: row = q*4 + reg (within wave's 16-strip), col = m.
        #pragma unroll
        for (int jt = 0; jt < 4; ++jt) {
            #pragma unroll
            for (int r = 0; r < 4; ++r) {
                G[(size_t)(i0 + w * 16 + q * 4 + r) * NN + j0 + jt * 16 + m] = acc[jt][r];
                if (bi == bj && jt == w && m == q * 4 + r)
                    nrm[i0 + w * 16 + m] = sqrtf(fmaxf(acc[jt][r], 0.f));
            }
        }
    } else {
        float* smem = (float*)AH;  // 4224 B needed <= 5120 B
        const int u = task - 288;
        const float* S = (u >= 16) ? p.Wsn : p.Wvn;
        float* Dt = (u >= 16) ? p.WsnT : p.WvnT;
        const int tile = u & 15;
        const int c0 = (tile & 3) * 32, r0 = (tile >> 2) * 32;
        const int tx = tid & 31, ty = tid >> 5;
        #pragma unroll
        for (int rr = ty; rr < 32; rr += 8)
            smem[rr * 33 + tx] = S[(size_t)(r0 + rr) * DD + c0 + tx];
        __syncthreads();
        #pragma unroll
        for (int rr = ty; rr < 32; rr += 8)
            Dt[(size_t)(c0 + rr) * DD + r0 + tx] = smem[tx * 33 + rr];
    }
}

// block-wide softmax (512 threads) over a 768-float LDS buffer, in place.
__device__ void block_softmax768(float* buf, int tid, float* red) {
    const int w = tid >> 6, lane = tid & 63;
    float v0 = buf[tid];
    float v1 = (tid < NN - 512) ? buf[tid + 512] : -3.4e38f;
    float m = wave_max(fmaxf(v0, v1));
    if (lane == 0) red[w] = m;
    __syncthreads();
    m = red[0];
    #pragma unroll
    for (int i = 1; i < 8; ++i) m = fmaxf(m, red[i]);
    float e0 = __expf(v0 - m);
    float e1 = (tid < NN - 512) ? __expf(v1 - m) : 0.f;
    float sw = wave_sum(e0 + e1);
    if (lane == 0) red[8 + w] = sw;
    __syncthreads();
    float s = 0.f;
    #pragma unroll
    for (int i = 0; i < 8; ++i) s += red[8 + i];
    const float inv = 1.f / s;
    buf[tid] = e0 * inv;
    if (tid < NN - 512) buf[tid + 512] = e1 * inv;
    __syncthreads();
}

// normalize 2 raw gram rows in LDS: val = G*10/max(ni*nj, eps)
__device__ void norm_rows(float (*buf)[NN], const float* __restrict__ nrm, int i0, int tid) {
    const float n0 = nrm[i0], n1 = nrm[i0 + 1];
    for (int k = tid; k < NN; k += 512) {
        const float nj = nrm[k];
        buf[0][k] = buf[0][k] * 10.f / fmaxf(n0 * nj, CEPS);
        buf[1][k] = buf[1][k] * 10.f / fmaxf(n1 * nj, CEPS);
    }
}

// node tail shared by node1 and the fused edge+node kernel.
// ep/ex: softmaxed edge rows in LDS. Computes out/outb rows i0,i0+1 and cvec.
__device__ void node_core(const float* __restrict__ P, float (*ep)[NN], float (*ex)[NN],
                          const float* __restrict__ WT, const float* __restrict__ b,
                          const float* __restrict__ g, const float* __restrict__ beta,
                          float* __restrict__ out, const float* __restrict__ W1e,
                          short* __restrict__ outb, float* __restrict__ cvec, int i0, int tid,
                          float (*pp)[2][DD], float (*xx)[2][DD], float (*qs)[DD],
                          float (*tps)[2][DD], float* red) {
    const int s = (tid >> 7) & 3, d = tid & 127;
    float p0 = 0.f, x0 = 0.f, p1 = 0.f, x1 = 0.f;
    const int kb = s * 192;
    #pragma unroll 4
    for (int kk = 0; kk < 192; ++kk) {
        const int k = kb + kk;
        const float pv = P[(size_t)k * DD + d];
        p0 = fmaf(ep[0][k], pv, p0);
        x0 = fmaf(ex[0][k], pv, x0);
        p1 = fmaf(ep[1][k], pv, p1);
        x1 = fmaf(ex[1][k], pv, x1);
    }
    pp[s][0][d] = p0; xx[s][0][d] = x0;
    pp[s][1][d] = p1; xx[s][1][d] = x1;
    __syncthreads();
    const int rr = (tid >> 7) & 1;
    float preg = 0.f;
    if (tid < 256) {
        float p = pp[0][rr][d] + pp[1][rr][d] + pp[2][rr][d] + pp[3][rr][d];
        float x = xx[0][rr][d] + xx[1][rr][d] + xx[2][rr][d] + xx[3][rr][d];
        qs[rr][d] = p + x;
        preg = p;
    }
    __syncthreads();
    {
        const int sc = tid >> 8, rr2 = (tid >> 7) & 1;
        float t = (sc == 0) ? b[d] : 0.f;
        const int c0 = sc * 64;
        #pragma unroll 4
        for (int c = c0; c < c0 + 64; ++c) t = fmaf(qs[rr2][c], WT[(size_t)c * DD + d], t);
        tps[sc][rr2][d] = t;
    }
    __syncthreads();
    float tval = 0.f;
    if (tid < 256) tval = tps[0][rr][d] + tps[1][rr][d];
    float sm = wave_sum(tid < 256 ? tval : 0.f);
    if ((tid & 63) == 0) red[tid >> 6] = sm;
    __syncthreads();
    if (tid < 256) tval -= (red[2 * rr] + red[2 * rr + 1]) * (1.f / DD);
    float s2 = wave_sum(tid < 256 ? tval * tval : 0.f);
    if ((tid & 63) == 0) red[8 + (tid >> 6)] = s2;
    __syncthreads();
    if (tid < 256) {
        const float var = (red[8 + 2 * rr] + red[8 + 2 * rr + 1]) * (1.f / DD);
        const float ln = tval * rsqrtf(var + 1e-5f) * g[d] + beta[d];
        const float val = fmaxf(ln, 0.f) + preg;
        out[(size_t)(i0 + rr) * DD + d] = val;
        outb[(size_t)(i0 + rr) * DD + d] = (short)f2bf(val);
        qs[rr][d] = val;
    }
    __syncthreads();
    if (tid < 256) {
        const int row = tid >> 7, r = (tid >> 4) & 7, l16 = tid & 15;
        float ssum = 0.f;
        #pragma unroll
        for (int t = 0; t < 8; ++t) {
            const int k = l16 + 16 * t;
            const float pv = qs[row][k];
            ssum = fmaf(W1e[r * DD + k], pv * pv, ssum);
        }
        #pragma unroll
        for (int o = 8; o; o >>= 1) ssum += __shfl_down(ssum, o, 16);
        if (l16 == 0) cvec[(size_t)(i0 + row) * HH + r] = ssum;
    }
}

// ---------------- K2: node1 (2 rows/block, 512 thr) ----------------
// Softmaxes raw gram rows (ve, se) once, MATERIALIZES them, then node update for vp.
__global__ __launch_bounds__(512) void node1_kernel(KParams p) {
    __shared__ __align__(16) float ep[2][NN], ex[2][NN];
    __shared__ __align__(16) float pp[4][2][DD], xx[4][2][DD];
    __shared__ __align__(16) float qs[2][DD], tps[2][2][DD];
    __shared__ float red[16];
    const int i0 = blockIdx.x * 2;
    const int tid = threadIdx.x;
    if (tid < 384) {  // two consecutive rows contiguous: 1536 floats = 384 float4
        ((float4*)ep)[tid] = ((const float4*)(p.simv + (size_t)i0 * NN))[tid];
        ((float4*)ex)[tid] = ((const float4*)(p.sima + (size_t)i0 * NN))[tid];
    }
    __syncthreads();
    norm_rows(ep, p.nrmv, i0, tid);
    norm_rows(ex, p.nrma, i0, tid);
    block_softmax768(ep[0], tid, red);
    block_softmax768(ep[1], tid, red);
    block_softmax768(ex[0], tid, red);
    block_softmax768(ex[1], tid, red);
    if (tid < 384) {  // materialize ve/se rows for the downstream kernels
        ((float4*)(p.ve + (size_t)i0 * NN))[tid] = ((float4*)ep)[tid];
        ((float4*)(p.se + (size_t)i0 * NN))[tid] = ((float4*)ex)[tid];
    }
    node_core(p.visual, ep, ex, p.WvnT, p.bvn, p.gvn, p.betavn, p.vp, p.Wve1, p.vpb, p.cvec1,
              i0, tid, pp, xx, qs, tps, red);
}

// edge logits + row softmax into Ls (LDS). Lv = pre-softmaxed last_edge rows.
__device__ void edge_core(const float* __restrict__ PR, const short* __restrict__ PRb,
                          const float* __restrict__ cvec, const float* __restrict__ W1,
                          const float* __restrict__ b1, const float* __restrict__ W2,
                          const float* __restrict__ b2, float invtemp, int i0, int tid,
                          float (*pi)[DD], float* w1s, short* a_sw, float (*Lv)[NN],
                          float (*Ls)[NN], float* red) {
    const int lane = tid & 63, wave = tid >> 6;
    if (tid < 256) {  // A fragments: m = il*8+r, k = t*32 + q2*8 + e
        const int t = tid >> 6, m = lane & 15, q2 = lane >> 4;
        const int il = m >> 3, r = m & 7;
        const int kb = t * 32 + q2 * 8;
        s8b av;
        #pragma unroll
        for (int e = 0; e < 8; ++e)
            av[e] = (short)f2bf(pi[il][kb + e] * w1s[r * DD + kb + e]);
        *(s8b*)&a_sw[(t * 64 + lane) * 8] = av;
    }
    __syncthreads();
    s8b af[4];
    #pragma unroll
    for (int t = 0; t < 4; ++t) af[t] = *(const s8b*)&a_sw[(t * 64 + lane) * 8];
    const int q = lane >> 4, n = lane & 15;
    const int rbase = (q & 1) * 4;
    const int il = q >> 1;
    const float4 ci4 = *(const float4*)&cvec[(size_t)(i0 + il) * HH + rbase];
    const float4 b14 = *(const float4*)&b1[rbase];
    const float4 w24 = *(const float4*)&W2[rbase];
    const float b2s = b2[0];
    #pragma unroll
    for (int s = 0; s < 6; ++s) {
        const int j = wave * 96 + s * 16 + n;
        f4v acc = {0.f, 0.f, 0.f, 0.f};
        #pragma unroll
        for (int t = 0; t < 4; ++t) {
            const s8b bf = *(const s8b*)(PRb + (size_t)j * DD + t * 32 + q * 8);
            acc = __builtin_amdgcn_mfma_f32_16x16x32_bf16(af[t], bf, acc, 0, 0, 0);
        }
        const float4 cj = *(const float4*)&cvec[(size_t)j * HH + rbase];
        float z[4];
        z[0] = ci4.x + cj.x - 2.f * acc[0] + b14.x;
        z[1] = ci4.y + cj.y - 2.f * acc[1] + b14.y;
        z[2] = ci4.z + cj.z - 2.f * acc[2] + b14.z;
        z[3] = ci4.w + cj.w - 2.f * acc[3] + b14.w;
        float s1 = z[0] + z[1] + z[2] + z[3];
        float s2 = z[0] * z[0] + z[1] * z[1] + z[2] * z[2] + z[3] * z[3];
        s1 += __shfl_xor(s1, 16, 64);
        s2 += __shfl_xor(s2, 16, 64);
        const float mean = s1 * (1.f / HH);
        const float var = fmaxf(s2 * (1.f / HH) - mean * mean, 0.f);
        const float istd = rsqrtf(var + 1e-5f);
        float a2 = 0.f;
        a2 = fmaf(fmaxf((z[0] - mean) * istd, 0.f), w24.x, a2);
        a2 = fmaf(fmaxf((z[1] - mean) * istd, 0.f), w24.y, a2);
        a2 = fmaf(fmaxf((z[2] - mean) * istd, 0.f), w24.z, a2);
        a2 = fmaf(fmaxf((z[3] - mean) * istd, 0.f), w24.w, a2);
        a2 += __shfl_xor(a2, 16, 64);
        const float tv = tanhf(a2 + b2s);
        const float lv = Lv[il][j];
        if ((q & 1) == 0) Ls[il][j] = tv * (lv + CEPS) * invtemp;
    }
    __syncthreads();
    block_softmax768(Ls[0], tid, red);
    block_softmax768(Ls[1], tid, red);
}

// ---------------- K3: edge1 + node2 fused (2 rows/block, 512 thr) ----------------
// edge1: ve2 rows = softmax(logits(vp)*(ve+eps)/VTEMP)  [ve pre-softmaxed]
// node2: sp rows  = node(semantic, ep=se rows [pre-softmaxed], ex=ve2 rows [in LDS])
__global__ __launch_bounds__(512) void edge_node_kernel(KParams p) {
    __shared__ __align__(16) float pi[2][DD];
    __shared__ __align__(16) float w1s[HH * DD];
    __shared__ __align__(16) short a_sw[4 * 64 * 8];
    __shared__ __align__(16) float Lv[2][NN];
    __shared__ __align__(16) float Ls[2][NN];
    __shared__ __align__(16) float ep[2][NN];
    __shared__ __align__(16) float pp[4][2][DD], xx[4][2][DD];
    __shared__ __align__(16) float qs[2][DD], tps[2][2][DD];
    __shared__ float red[16];
    const int i0 = blockIdx.x * 2;
    const int tid = threadIdx.x;
    if (tid < 256) {
        pi[tid >> 7][tid & 127] = p.vp[(size_t)(i0 + (tid >> 7)) * DD + (tid & 127)];
        ((float4*)w1s)[tid] = ((const float4*)p.Wve1)[tid];
    }
    if (tid < 384) {
        ((float4*)Lv)[tid] = ((const float4*)(p.ve + (size_t)i0 * NN))[tid];
        ((float4*)ep)[tid] = ((const float4*)(p.se + (size_t)i0 * NN))[tid];
    }
    __syncthreads();
    edge_core(p.vp, p.vpb, p.cvec1, p.Wve1, p.bve1, p.Wve2, p.bve2, 0.1f, i0, tid, pi, w1s,
              a_sw, Lv, Ls, red);
    if (tid < 384)  // write ve2 rows
        ((float4*)(p.ve2 + (size_t)i0 * NN))[tid] = ((float4*)Ls)[tid];
    // node2: ep = se rows (pre-softmaxed), ex = Ls (= ve2 rows, still in LDS)
    node_core(p.semantic, ep, Ls, p.WsnT, p.bsn, p.gsn, p.betasn, p.sp, p.Wse1, p.spb,
              p.cvec2, i0, tid, pp, xx, qs, tps, red);
}

// ---------------- K4: edge2 (2 rows/block, 512 thr) ----------------
__global__ __launch_bounds__(512) void edge2_kernel(KParams p) {
    __shared__ __align__(16) float pi[2][DD];
    __shared__ __align__(16) float w1s[HH * DD];
    __shared__ __align__(16) short a_sw[4 * 64 * 8];
    __shared__ __align__(16) float Lv[2][NN];
    __shared__ __align__(16) float Ls[2][NN];
    __shared__ float red[16];
    const int i0 = blockIdx.x * 2;
    const int tid = threadIdx.x;
    if (tid < 256) {
        pi[tid >> 7][tid & 127] = p.sp[(size_t)(i0 + (tid >> 7)) * DD + (tid & 127)];
        ((float4*)w1s)[tid] = ((const float4*)p.Wse1)[tid];
    }
    if (tid < 384)
        ((float4*)Lv)[tid] = ((const float4*)(p.se + (size_t)i0 * NN))[tid];
    __syncthreads();
    edge_core(p.sp, p.spb, p.cvec2, p.Wse1, p.bse1, p.Wse2, p.bse2, 0.1f, i0, tid, pi, w1s,
              a_sw, Lv, Ls, red);
    float* d0 = p.se2 + (size_t)i0 * NN;
    float* d1 = p.se2 + (size_t)(i0 + 1) * NN;
    d0[tid] = Ls[0][tid];
    d1[tid] = Ls[1][tid];
    if (tid < NN - 512) {
        d0[tid + 512] = Ls[0][tid + 512];
        d1[tid + 512] = Ls[1][tid + 512];
    }
}

extern "C" void kernel_launch(void* const* d_in, const int* in_sizes, int n_in, void* d_out,
                              int out_size, void* d_ws, size_t ws_size, hipStream_t stream) {
    KParams kp;
    kp.visual    = (const float*)d_in[0];
    kp.semantic  = (const float*)d_in[1];
    kp.attribute = (const float*)d_in[2];
    kp.Wvn  = (const float*)d_in[3];
    kp.bvn  = (const float*)d_in[4];
    kp.gvn  = (const float*)d_in[5];
    kp.betavn = (const float*)d_in[6];
    kp.Wve1 = (const float*)d_in[7];
    kp.bve1 = (const float*)d_in[8];
    kp.Wve2 = (const float*)d_in[9];
    kp.bve2 = (const float*)d_in[10];
    kp.Wsn  = (const float*)d_in[11];
    kp.bsn  = (const float*)d_in[12];
    kp.gsn  = (const float*)d_in[13];
    kp.betasn = (const float*)d_in[14];
    kp.Wse1 = (const float*)d_in[15];
    kp.bse1 = (const float*)d_in[16];
    kp.Wse2 = (const float*)d_in[17];
    kp.bse2 = (const float*)d_in[18];

    float* out = (float*)d_out;
    kp.vp  = out;              // 768*128
    kp.sp  = out + 98304;      // 768*128
    kp.ve2 = out + 196608;     // 768*768
    kp.se2 = out + 786432;     // 768*768

    float* ws = (float*)d_ws;
    kp.simv  = ws;             // 768*768 RAW gram
    kp.sima  = ws + 589824;
    kp.ve    = ws + 1179648;   // materialized softmax(norm(simv))
    kp.se    = ws + 1769472;   // materialized softmax(norm(sima))
    kp.WvnT  = ws + 2949120;   // 128*128
    kp.WsnT  = ws + 2965504;
    kp.cvec1 = ws + 2981888;   // 768*8
    kp.cvec2 = ws + 2988032;
    kp.vpb   = (short*)(ws + 2994176);  // 768*128 bf16 (49152 floats)
    kp.spb   = (short*)(ws + 3043328);
    kp.nrmv  = ws + 3092480;   // 768
    kp.nrma  = ws + 3093248;   // 768

    gram_mfma_kernel<<<320, 256, 0, stream>>>(kp);
    node1_kernel<<<NN / 2, 512, 0, stream>>>(kp);
    edge_node_kernel<<<NN / 2, 512, 0, stream>>>(kp);
    edge2_kernel<<<NN / 2, 512, 0, stream>>>(kp);
}

// Round 9
// 176.883 us; speedup vs baseline: 1.3260x; 1.0401x over previous
//
#include <hip/hip_runtime.h>
#include <math.h>

#define NN 768
#define DD 128
#define AA 312
#define HH 8
#define CEPS 1e-8f

typedef __attribute__((ext_vector_type(8))) short s8b;   // 8 x bf16
typedef __attribute__((ext_vector_type(4))) float f4v;   // MFMA C/D

__device__ __forceinline__ float wave_sum(float v) {
    #pragma unroll
    for (int o = 32; o; o >>= 1) v += __shfl_down(v, o, 64);
    return v;
}
__device__ __forceinline__ float wave_max(float v) {
    #pragma unroll
    for (int o = 32; o; o >>= 1) v = fmaxf(v, __shfl_down(v, o, 64));
    return v;
}
__device__ __forceinline__ unsigned short f2bf(float f) {
    unsigned u = __float_as_uint(f);
    u += 0x7FFFu + ((u >> 16) & 1u);
    return (unsigned short)(u >> 16);
}

struct KParams {
    const float *visual, *semantic, *attribute;
    const float *Wvn, *bvn, *gvn, *betavn, *Wve1, *bve1, *Wve2, *bve2;
    const float *Wsn, *bsn, *gsn, *betasn, *Wse1, *bse1, *Wse2, *bse2;
    float *vp, *sp, *ve2, *se2;
    float *simv, *sima, *WvnT, *WsnT, *cvec1, *cvec2;
    float *nrmv, *nrma, *ve, *se;
    short *vpb, *spb;
};

// ---------------- K1: MFMA bf16x2-split gram (raw G) + diag norms + W transposes -----------
__global__ __launch_bounds__(256) void gram_mfma_kernel(KParams p) {
    __shared__ __align__(16) unsigned short AH[64 * 40];
    __shared__ __align__(16) unsigned short AL[64 * 40];
    __shared__ __align__(16) unsigned short BH[64 * 40];
    __shared__ __align__(16) unsigned short BL[64 * 40];
    const int task = blockIdx.x;
    const int tid = threadIdx.x;
    if (task < 288) {
        const bool isv = (task < 144);
        const int tt = isv ? task : task - 144;
        const int bi = tt / 12, bj = tt % 12;
        const float* M = isv ? p.visual : p.attribute;
        float* G = isv ? p.simv : p.sima;
        float* nrm = isv ? p.nrmv : p.nrma;
        const int K = isv ? DD : AA;
        const int i0 = bi * 64, j0 = bj * 64;
        const int w = tid >> 6, lane = tid & 63;
        const int m = lane & 15, q = lane >> 4;
        f4v acc[4] = {{0.f, 0.f, 0.f, 0.f}, {0.f, 0.f, 0.f, 0.f},
                      {0.f, 0.f, 0.f, 0.f}, {0.f, 0.f, 0.f, 0.f}};
        const int nchunk = (K + 31) >> 5;
        const int srow = tid >> 2, sq = (tid & 3) * 8;
        for (int c = 0; c < nchunk; ++c) {
            const int kc = c * 32;
            __syncthreads();
            #pragma unroll
            for (int h = 0; h < 2; ++h) {
                const int col = sq + h * 4;
                float4 a = {0.f, 0.f, 0.f, 0.f}, b = {0.f, 0.f, 0.f, 0.f};
                if (kc + col + 4 <= K) {
                    a = *(const float4*)(M + (size_t)(i0 + srow) * K + kc + col);
                    b = *(const float4*)(M + (size_t)(j0 + srow) * K + kc + col);
                }
                const float av[4] = {a.x, a.y, a.z, a.w};
                const float bv[4] = {b.x, b.y, b.z, b.w};
                #pragma unroll
                for (int e = 0; e < 4; ++e) {
                    const unsigned short ah = f2bf(av[e]);
                    const float ahf = __uint_as_float((unsigned)ah << 16);
                    const unsigned short al = f2bf(av[e] - ahf);
                    const unsigned short bh = f2bf(bv[e]);
                    const float bhf = __uint_as_float((unsigned)bh << 16);
                    const unsigned short bl = f2bf(bv[e] - bhf);
                    AH[srow * 40 + col + e] = ah;
                    AL[srow * 40 + col + e] = al;
                    BH[srow * 40 + col + e] = bh;
                    BL[srow * 40 + col + e] = bl;
                }
            }
            __syncthreads();
            const s8b ah8 = *(const s8b*)&AH[(w * 16 + m) * 40 + q * 8];
            const s8b al8 = *(const s8b*)&AL[(w * 16 + m) * 40 + q * 8];
            #pragma unroll
            for (int jt = 0; jt < 4; ++jt) {
                const s8b bh8 = *(const s8b*)&BH[(jt * 16 + m) * 40 + q * 8];
                const s8b bl8 = *(const s8b*)&BL[(jt * 16 + m) * 40 + q * 8];
                acc[jt] = __builtin_amdgcn_mfma_f32_16x16x32_bf16(ah8, bh8, acc[jt], 0, 0, 0);
                acc[jt] = __builtin_amdgcn_mfma_f32_16x16x32_bf16(ah8, bl8, acc[jt], 0, 0, 0);
                acc[jt] = __builtin_amdgcn_mfma_f32_16x16x32_bf16(al8, bh8, acc[jt], 0, 0, 0);
            }
        }
        #pragma unroll
        for (int jt = 0; jt < 4; ++jt) {
            #pragma unroll
            for (int r = 0; r < 4; ++r) {
                G[(size_t)(i0 + w * 16 + q * 4 + r) * NN + j0 + jt * 16 + m] = acc[jt][r];
                if (bi == bj && jt == w && m == q * 4 + r)
                    nrm[i0 + w * 16 + m] = sqrtf(fmaxf(acc[jt][r], 0.f));
            }
        }
    } else {
        float* smem = (float*)AH;
        const int u = task - 288;
        const float* S = (u >= 16) ? p.Wsn : p.Wvn;
        float* Dt = (u >= 16) ? p.WsnT : p.WvnT;
        const int tile = u & 15;
        const int c0 = (tile & 3) * 32, r0 = (tile >> 2) * 32;
        const int tx = tid & 31, ty = tid >> 5;
        #pragma unroll
        for (int rr = ty; rr < 32; rr += 8)
            smem[rr * 33 + tx] = S[(size_t)(r0 + rr) * DD + c0 + tx];
        __syncthreads();
        #pragma unroll
        for (int rr = ty; rr < 32; rr += 8)
            Dt[(size_t)(c0 + rr) * DD + r0 + tx] = smem[tx * 33 + rr];
    }
}

// Two concurrent 768-float softmaxes: waves 0-3 on A, waves 4-7 on B. 3 barriers.
__device__ void softmax768_pair(float* A, float* B, int tid, float* red) {
    float* buf = (tid < 256) ? A : B;
    const int st = tid & 255;
    const int g = tid >> 8;
    const int w4 = (tid >> 6) & 3;
    float v0 = buf[st], v1 = buf[st + 256], v2 = buf[st + 512];
    float m = wave_max(fmaxf(fmaxf(v0, v1), v2));
    if ((tid & 63) == 0) red[g * 8 + w4] = m;
    __syncthreads();
    m = fmaxf(fmaxf(red[g * 8], red[g * 8 + 1]), fmaxf(red[g * 8 + 2], red[g * 8 + 3]));
    float e0 = __expf(v0 - m), e1 = __expf(v1 - m), e2 = __expf(v2 - m);
    float sw = wave_sum(e0 + e1 + e2);
    if ((tid & 63) == 0) red[g * 8 + 4 + w4] = sw;
    __syncthreads();
    const float s = red[g * 8 + 4] + red[g * 8 + 5] + red[g * 8 + 6] + red[g * 8 + 7];
    const float inv = 1.f / s;
    buf[st] = e0 * inv;
    buf[st + 256] = e1 * inv;
    buf[st + 512] = e2 * inv;
    __syncthreads();
}

// normalize 2 raw gram rows in LDS: val = G*10/max(ni*nj, eps). Thread t owns {t, t+512}.
__device__ void norm_rows(float (*buf)[NN], const float* __restrict__ nrm, int i0, int tid) {
    const float n0 = nrm[i0], n1 = nrm[i0 + 1];
    for (int k = tid; k < NN; k += 512) {
        const float nj = nrm[k];
        buf[0][k] = buf[0][k] * 10.f / fmaxf(n0 * nj, CEPS);
        buf[1][k] = buf[1][k] * 10.f / fmaxf(n1 * nj, CEPS);
    }
}

// node tail. ep/ex: softmaxed rows in LDS. ppart/xpart: float[8*260] padded partial slabs.
__device__ void node_core(const float* __restrict__ P, float (*ep)[NN], float (*ex)[NN],
                          const float* __restrict__ WT, const float* __restrict__ b,
                          const float* __restrict__ g, const float* __restrict__ beta,
                          float* __restrict__ out, const float* __restrict__ W1e,
                          short* __restrict__ outb, float* __restrict__ cvec, int i0, int tid,
                          float* ppart, float* xpart, float (*qs)[DD], float (*tps)[2][DD],
                          float* red) {
    // aggregation: 8 k-groups (one per wave) x 64 d-pairs; float2 P loads.
    {
        const int kg = tid >> 6, dp = tid & 63, d0 = dp * 2;
        const float2* P2 = (const float2*)P;
        float a00 = 0.f, a01 = 0.f, a10 = 0.f, a11 = 0.f;
        float b00 = 0.f, b01 = 0.f, b10 = 0.f, b11 = 0.f;
        const int kb = kg * 96;
        #pragma unroll 8
        for (int i = 0; i < 96; ++i) {
            const int k = kb + i;
            const float2 pv = P2[(size_t)k * 64 + dp];
            const float e0 = ep[0][k], e1 = ep[1][k];
            const float f0 = ex[0][k], f1 = ex[1][k];
            a00 = fmaf(e0, pv.x, a00); a01 = fmaf(e0, pv.y, a01);
            a10 = fmaf(e1, pv.x, a10); a11 = fmaf(e1, pv.y, a11);
            b00 = fmaf(f0, pv.x, b00); b01 = fmaf(f0, pv.y, b01);
            b10 = fmaf(f1, pv.x, b10); b11 = fmaf(f1, pv.y, b11);
        }
        float* pp = ppart + kg * 260;  // [2][130] slab, stride 260 == 4 (mod 32) banks
        float* xp = xpart + kg * 260;
        pp[d0] = a00; pp[d0 + 1] = a01; pp[130 + d0] = a10; pp[130 + d0 + 1] = a11;
        xp[d0] = b00; xp[d0 + 1] = b01; xp[130 + d0] = b10; xp[130 + d0 + 1] = b11;
    }
    __syncthreads();
    const int rr = (tid >> 7) & 1, d = tid & 127;
    float preg = 0.f;
    if (tid < 256) {
        float p = 0.f, x = 0.f;
        #pragma unroll
        for (int kk = 0; kk < 8; ++kk) {
            p += ppart[kk * 260 + rr * 130 + d];
            x += xpart[kk * 260 + rr * 130 + d];
        }
        qs[rr][d] = p + x;
        preg = p;
    }
    __syncthreads();
    {
        const int sc = tid >> 8, rr2 = (tid >> 7) & 1;
        float t = (sc == 0) ? b[d] : 0.f;
        const int c0 = sc * 64;
        #pragma unroll 4
        for (int c = c0; c < c0 + 64; ++c) t = fmaf(qs[rr2][c], WT[(size_t)c * DD + d], t);
        tps[sc][rr2][d] = t;
    }
    __syncthreads();
    float tval = 0.f;
    if (tid < 256) tval = tps[0][rr][d] + tps[1][rr][d];
    float sm = wave_sum(tid < 256 ? tval : 0.f);
    if ((tid & 63) == 0) red[tid >> 6] = sm;
    __syncthreads();
    if (tid < 256) tval -= (red[2 * rr] + red[2 * rr + 1]) * (1.f / DD);
    float s2 = wave_sum(tid < 256 ? tval * tval : 0.f);
    if ((tid & 63) == 0) red[8 + (tid >> 6)] = s2;
    __syncthreads();
    if (tid < 256) {
        const float var = (red[8 + 2 * rr] + red[8 + 2 * rr + 1]) * (1.f / DD);
        const float ln = tval * rsqrtf(var + 1e-5f) * g[d] + beta[d];
        const float val = fmaxf(ln, 0.f) + preg;
        out[(size_t)(i0 + rr) * DD + d] = val;
        outb[(size_t)(i0 + rr) * DD + d] = (short)f2bf(val);
        qs[rr][d] = val;
    }
    __syncthreads();
    if (tid < 256) {
        const int row = tid >> 7, r = (tid >> 4) & 7, l16 = tid & 15;
        float ssum = 0.f;
        #pragma unroll
        for (int t = 0; t < 8; ++t) {
            const int k = l16 + 16 * t;
            const float pv = qs[row][k];
            ssum = fmaf(W1e[r * DD + k], pv * pv, ssum);
        }
        #pragma unroll
        for (int o = 8; o; o >>= 1) ssum += __shfl_down(ssum, o, 16);
        if (l16 == 0) cvec[(size_t)(i0 + row) * HH + r] = ssum;
    }
}

// ---------------- K2: node1 (2 rows/block, 512 thr) ----------------
__global__ __launch_bounds__(512) void node1_kernel(KParams p) {
    __shared__ __align__(16) float ep[2][NN], ex[2][NN];
    __shared__ __align__(16) float ppart[8 * 260], xpart[8 * 260];
    __shared__ __align__(16) float qs[2][DD], tps[2][2][DD];
    __shared__ float red[16];
    const int i0 = blockIdx.x * 2;
    const int tid = threadIdx.x;
    if (tid < 384) {
        ((float4*)ep)[tid] = ((const float4*)(p.simv + (size_t)i0 * NN))[tid];
        ((float4*)ex)[tid] = ((const float4*)(p.sima + (size_t)i0 * NN))[tid];
    }
    __syncthreads();
    norm_rows(ep, p.nrmv, i0, tid);
    norm_rows(ex, p.nrma, i0, tid);
    __syncthreads();
    softmax768_pair(ep[0], ex[0], tid, red);
    softmax768_pair(ep[1], ex[1], tid, red);
    if (tid < 384) {  // materialize ve/se rows for downstream kernels
        ((float4*)(p.ve + (size_t)i0 * NN))[tid] = ((float4*)ep)[tid];
        ((float4*)(p.se + (size_t)i0 * NN))[tid] = ((float4*)ex)[tid];
    }
    node_core(p.visual, ep, ex, p.WvnT, p.bvn, p.gvn, p.betavn, p.vp, p.Wve1, p.vpb, p.cvec1,
              i0, tid, ppart, xpart, qs, tps, red);
}

// edge logits into Ls (LDS, unsoftmaxed). Lv = pre-softmaxed last_edge rows.
__device__ void edge_core(const short* __restrict__ PRb, const float* __restrict__ cvec,
                          const float* __restrict__ W1, const float* __restrict__ b1,
                          const float* __restrict__ W2, const float* __restrict__ b2,
                          float invtemp, int i0, int tid, float (*pi)[DD], float* w1s,
                          short* a_sw, float (*Lv)[NN], float (*Ls)[NN]) {
    const int lane = tid & 63, wave = tid >> 6;
    if (tid < 256) {  // A fragments: m = il*8+r, k = t*32 + q2*8 + e
        const int t = tid >> 6, m = lane & 15, q2 = lane >> 4;
        const int il = m >> 3, r = m & 7;
        const int kb = t * 32 + q2 * 8;
        s8b av;
        #pragma unroll
        for (int e = 0; e < 8; ++e)
            av[e] = (short)f2bf(pi[il][kb + e] * w1s[r * DD + kb + e]);
        *(s8b*)&a_sw[(t * 64 + lane) * 8] = av;
    }
    __syncthreads();
    s8b af[4];
    #pragma unroll
    for (int t = 0; t < 4; ++t) af[t] = *(const s8b*)&a_sw[(t * 64 + lane) * 8];
    const int q = lane >> 4, n = lane & 15;
    const int rbase = (q & 1) * 4;
    const int il = q >> 1;
    const float4 ci4 = *(const float4*)&cvec[(size_t)(i0 + il) * HH + rbase];
    const float4 b14 = *(const float4*)&b1[rbase];
    const float4 w24 = *(const float4*)&W2[rbase];
    const float b2s = b2[0];
    #pragma unroll
    for (int s = 0; s < 6; ++s) {
        const int j = wave * 96 + s * 16 + n;
        f4v acc = {0.f, 0.f, 0.f, 0.f};
        #pragma unroll
        for (int t = 0; t < 4; ++t) {
            const s8b bf = *(const s8b*)(PRb + (size_t)j * DD + t * 32 + q * 8);
            acc = __builtin_amdgcn_mfma_f32_16x16x32_bf16(af[t], bf, acc, 0, 0, 0);
        }
        const float4 cj = *(const float4*)&cvec[(size_t)j * HH + rbase];
        float z[4];
        z[0] = ci4.x + cj.x - 2.f * acc[0] + b14.x;
        z[1] = ci4.y + cj.y - 2.f * acc[1] + b14.y;
        z[2] = ci4.z + cj.z - 2.f * acc[2] + b14.z;
        z[3] = ci4.w + cj.w - 2.f * acc[3] + b14.w;
        float s1 = z[0] + z[1] + z[2] + z[3];
        float s2 = z[0] * z[0] + z[1] * z[1] + z[2] * z[2] + z[3] * z[3];
        s1 += __shfl_xor(s1, 16, 64);
        s2 += __shfl_xor(s2, 16, 64);
        const float mean = s1 * (1.f / HH);
        const float var = fmaxf(s2 * (1.f / HH) - mean * mean, 0.f);
        const float istd = rsqrtf(var + 1e-5f);
        float a2 = 0.f;
        a2 = fmaf(fmaxf((z[0] - mean) * istd, 0.f), w24.x, a2);
        a2 = fmaf(fmaxf((z[1] - mean) * istd, 0.f), w24.y, a2);
        a2 = fmaf(fmaxf((z[2] - mean) * istd, 0.f), w24.z, a2);
        a2 = fmaf(fmaxf((z[3] - mean) * istd, 0.f), w24.w, a2);
        a2 += __shfl_xor(a2, 16, 64);
        const float tv = tanhf(a2 + b2s);
        const float lv = Lv[il][j];
        if ((q & 1) == 0) Ls[il][j] = tv * (lv + CEPS) * invtemp;
    }
    __syncthreads();
}

// ---------------- K3: edge1 + node2 fused (2 rows/block, 512 thr) ----------------
__global__ __launch_bounds__(512) void edge_node_kernel(KParams p) {
    __shared__ __align__(16) float pi[2][DD];
    __shared__ __align__(16) float w1s[HH * DD];
    __shared__ __align__(16) short a_sw[4 * 64 * 8];
    __shared__ __align__(16) float Lv[2][NN];
    __shared__ __align__(16) float Ls[2][NN];
    __shared__ __align__(16) float ep[2][NN];
    __shared__ __align__(16) float ppart[8 * 260], xpart[8 * 260];
    __shared__ __align__(16) float qs[2][DD], tps[2][2][DD];
    __shared__ float red[16];
    const int i0 = blockIdx.x * 2;
    const int tid = threadIdx.x;
    if (tid < 256) {
        pi[tid >> 7][tid & 127] = p.vp[(size_t)(i0 + (tid >> 7)) * DD + (tid & 127)];
        ((float4*)w1s)[tid] = ((const float4*)p.Wve1)[tid];
    }
    if (tid < 384) {
        ((float4*)Lv)[tid] = ((const float4*)(p.ve + (size_t)i0 * NN))[tid];
        ((float4*)ep)[tid] = ((const float4*)(p.se + (size_t)i0 * NN))[tid];
    }
    __syncthreads();
    edge_core(p.vpb, p.cvec1, p.Wve1, p.bve1, p.Wve2, p.bve2, 0.1f, i0, tid, pi, w1s, a_sw,
              Lv, Ls);
    softmax768_pair(Ls[0], Ls[1], tid, red);
    if (tid < 384)  // write ve2 rows
        ((float4*)(p.ve2 + (size_t)i0 * NN))[tid] = ((float4*)Ls)[tid];
    // node2: ep = se rows (pre-softmaxed), ex = Ls (= ve2 rows, in LDS)
    node_core(p.semantic, ep, Ls, p.WsnT, p.bsn, p.gsn, p.betasn, p.sp, p.Wse1, p.spb,
              p.cvec2, i0, tid, ppart, xpart, qs, tps, red);
}

// ---------------- K4: edge2 (2 rows/block, 512 thr) ----------------
__global__ __launch_bounds__(512) void edge2_kernel(KParams p) {
    __shared__ __align__(16) float pi[2][DD];
    __shared__ __align__(16) float w1s[HH * DD];
    __shared__ __align__(16) short a_sw[4 * 64 * 8];
    __shared__ __align__(16) float Lv[2][NN];
    __shared__ __align__(16) float Ls[2][NN];
    __shared__ float red[16];
    const int i0 = blockIdx.x * 2;
    const int tid = threadIdx.x;
    if (tid < 256) {
        pi[tid >> 7][tid & 127] = p.sp[(size_t)(i0 + (tid >> 7)) * DD + (tid & 127)];
        ((float4*)w1s)[tid] = ((const float4*)p.Wse1)[tid];
    }
    if (tid < 384)
        ((float4*)Lv)[tid] = ((const float4*)(p.se + (size_t)i0 * NN))[tid];
    __syncthreads();
    edge_core(p.spb, p.cvec2, p.Wse1, p.bse1, p.Wse2, p.bse2, 0.1f, i0, tid, pi, w1s, a_sw,
              Lv, Ls);
    softmax768_pair(Ls[0], Ls[1], tid, red);
    float* d0 = p.se2 + (size_t)i0 * NN;
    float* d1 = p.se2 + (size_t)(i0 + 1) * NN;
    d0[tid] = Ls[0][tid];
    d1[tid] = Ls[1][tid];
    if (tid < NN - 512) {
        d0[tid + 512] = Ls[0][tid + 512];
        d1[tid + 512] = Ls[1][tid + 512];
    }
}

extern "C" void kernel_launch(void* const* d_in, const int* in_sizes, int n_in, void* d_out,
                              int out_size, void* d_ws, size_t ws_size, hipStream_t stream) {
    KParams kp;
    kp.visual    = (const float*)d_in[0];
    kp.semantic  = (const float*)d_in[1];
    kp.attribute = (const float*)d_in[2];
    kp.Wvn  = (const float*)d_in[3];
    kp.bvn  = (const float*)d_in[4];
    kp.gvn  = (const float*)d_in[5];
    kp.betavn = (const float*)d_in[6];
    kp.Wve1 = (const float*)d_in[7];
    kp.bve1 = (const float*)d_in[8];
    kp.Wve2 = (const float*)d_in[9];
    kp.bve2 = (const float*)d_in[10];
    kp.Wsn  = (const float*)d_in[11];
    kp.bsn  = (const float*)d_in[12];
    kp.gsn  = (const float*)d_in[13];
    kp.betasn = (const float*)d_in[14];
    kp.Wse1 = (const float*)d_in[15];
    kp.bse1 = (const float*)d_in[16];
    kp.Wse2 = (const float*)d_in[17];
    kp.bse2 = (const float*)d_in[18];

    float* out = (float*)d_out;
    kp.vp  = out;              // 768*128
    kp.sp  = out + 98304;      // 768*128
    kp.ve2 = out + 196608;     // 768*768
    kp.se2 = out + 786432;     // 768*768

    float* ws = (float*)d_ws;
    kp.simv  = ws;             // 768*768 RAW gram
    kp.sima  = ws + 589824;
    kp.ve    = ws + 1179648;   // materialized softmax(norm(simv))
    kp.se    = ws + 1769472;   // materialized softmax(norm(sima))
    kp.WvnT  = ws + 2949120;   // 128*128
    kp.WsnT  = ws + 2965504;
    kp.cvec1 = ws + 2981888;   // 768*8
    kp.cvec2 = ws + 2988032;
    kp.vpb   = (short*)(ws + 2994176);  // 768*128 bf16 (49152 floats)
    kp.spb   = (short*)(ws + 3043328);
    kp.nrmv  = ws + 3092480;   // 768
    kp.nrma  = ws + 3093248;   // 768

    gram_mfma_kernel<<<320, 256, 0, stream>>>(kp);
    node1_kernel<<<NN / 2, 512, 0, stream>>>(kp);
    edge_node_kernel<<<NN / 2, 512, 0, stream>>>(kp);
    edge2_kernel<<<NN / 2, 512, 0, stream>>>(kp);
}